// Round 1
// baseline (1463.736 us; speedup 1.0000x reference)
//
#include <hip/hip_runtime.h>
#include <cstdint>
#include <cmath>

#define D 256
#define NEG 0.2f

__device__ __forceinline__ unsigned fflip(float f){
    unsigned u = __float_as_uint(f);
    return (u & 0x80000000u) ? ~u : (u | 0x80000000u);
}
__device__ __forceinline__ float funflip(unsigned v){
    unsigned u = (v & 0x80000000u) ? (v ^ 0x80000000u) : ~v;
    return __uint_as_float(u);
}

// zero d_out, smax (flip-encoded -inf == 0), ssum
__global__ void init_kernel(float4* out4, size_t n4, unsigned* __restrict__ smax,
                            float* __restrict__ ssum, size_t N){
    size_t i = (size_t)blockIdx.x*blockDim.x + threadIdx.x;
    size_t stride = (size_t)gridDim.x*blockDim.x;
    for (size_t j = i; j < n4; j += stride) out4[j] = make_float4(0.f,0.f,0.f,0.f);
    for (size_t j = i; j < N; j += stride){ smax[j] = 0u; ssum[j] = 0.f; }
}

// el = feat@Wsrc + bsrc (z=0), er = feat@Wdst + bdst (z=1)
// 64x64 tile, BK=32, 256 threads, 4x4 microtile per thread
__global__ __launch_bounds__(256) void proj_kernel(
    const float* __restrict__ feat,
    const float* __restrict__ Wsrc, const float* __restrict__ bsrc,
    const float* __restrict__ Wdst, const float* __restrict__ bdst,
    float* __restrict__ el, float* __restrict__ er, int N)
{
    const int which = blockIdx.z;
    const float* __restrict__ W    = which ? Wdst : Wsrc;
    const float* __restrict__ bias = which ? bdst : bsrc;
    float* __restrict__ out        = which ? er : el;

    const int row0 = blockIdx.x * 64;
    const int col0 = blockIdx.y * 64;

    __shared__ float As[64][36];   // +4 pad: 144B row stride (16B aligned, banks spread)
    __shared__ float Bs[32][68];   // +4 pad

    const int tid = threadIdx.x;
    const int tx = tid & 15;       // col group
    const int ty = tid >> 4;       // row group
    float acc[4][4] = {};

    const int arow = tid >> 3;          // 0..31
    const int af4  = (tid & 7) * 4;     // 0..28
    const int brow = tid >> 4;          // 0..15
    const int bf4  = (tid & 15) * 4;    // 0..60

    for (int k0 = 0; k0 < D; k0 += 32) {
        #pragma unroll
        for (int rr = 0; rr < 2; ++rr) {
            int r = arow + rr*32;
            int gr = row0 + r;
            float4 v = make_float4(0.f,0.f,0.f,0.f);
            if (gr < N) v = *(const float4*)(feat + (size_t)gr*D + k0 + af4);
            *(float4*)&As[r][af4] = v;
        }
        #pragma unroll
        for (int rr = 0; rr < 2; ++rr) {
            int r = brow + rr*16;
            float4 v = *(const float4*)(W + (size_t)(k0 + r)*D + col0 + bf4);
            *(float4*)&Bs[r][bf4] = v;
        }
        __syncthreads();
        #pragma unroll
        for (int kk = 0; kk < 32; ++kk) {
            float a[4], b[4];
            #pragma unroll
            for (int i = 0; i < 4; ++i) a[i] = As[ty*4+i][kk];
            #pragma unroll
            for (int j = 0; j < 4; ++j) b[j] = Bs[kk][tx*4+j];
            #pragma unroll
            for (int i = 0; i < 4; ++i)
                #pragma unroll
                for (int j = 0; j < 4; ++j)
                    acc[i][j] += a[i]*b[j];
        }
        __syncthreads();
    }
    #pragma unroll
    for (int i = 0; i < 4; ++i) {
        int gr = row0 + ty*4 + i;
        if (gr >= N) continue;
        int gc = col0 + tx*4;
        float4 b4 = *(const float4*)(bias + gc);
        float4 v = make_float4(acc[i][0]+b4.x, acc[i][1]+b4.y,
                               acc[i][2]+b4.z, acc[i][3]+b4.w);
        *(float4*)(out + (size_t)gr*D + gc) = v;
    }
}

// one wave per edge: score[e] = dot(leakyrelu(el[src]+er[dst]), attn); atomicMax smax[dst]
__global__ __launch_bounds__(256) void score_kernel(
    const float* __restrict__ el, const float* __restrict__ er,
    const float* __restrict__ attn, const int* __restrict__ src,
    const int* __restrict__ dst, float* __restrict__ score,
    unsigned* __restrict__ smax, int E)
{
    int e = blockIdx.x*4 + (threadIdx.x >> 6);
    if (e >= E) return;
    int lane = threadIdx.x & 63;
    int s = src[e], d = dst[e];
    float4 l4 = *(const float4*)(el + (size_t)s*D + lane*4);
    float4 r4 = *(const float4*)(er + (size_t)d*D + lane*4);
    float4 a4 = *(const float4*)(attn + lane*4);
    float x, acc = 0.f;
    x = l4.x + r4.x; acc += (x > 0.f ? x : NEG*x) * a4.x;
    x = l4.y + r4.y; acc += (x > 0.f ? x : NEG*x) * a4.y;
    x = l4.z + r4.z; acc += (x > 0.f ? x : NEG*x) * a4.z;
    x = l4.w + r4.w; acc += (x > 0.f ? x : NEG*x) * a4.w;
    #pragma unroll
    for (int off = 32; off > 0; off >>= 1) acc += __shfl_xor(acc, off, 64);
    if (lane == 0){
        score[e] = acc;
        atomicMax(&smax[d], fflip(acc));
    }
}

// one thread per edge: ssum[dst] += exp(score - smax[dst])
__global__ void expsum_kernel(const float* __restrict__ score,
                              const int* __restrict__ dst,
                              const unsigned* __restrict__ smax,
                              float* __restrict__ ssum, int E){
    int e = blockIdx.x*blockDim.x + threadIdx.x;
    if (e >= E) return;
    int d = dst[e];
    float m = funflip(smax[d]);
    atomicAdd(&ssum[d], __expf(score[e] - m));
}

// one wave per edge: out[dst] += a * el[src]
__global__ __launch_bounds__(256) void aggregate_kernel(
    const float* __restrict__ el, const float* __restrict__ score,
    const int* __restrict__ src, const int* __restrict__ dst,
    const unsigned* __restrict__ smax, const float* __restrict__ ssum,
    float* __restrict__ out, int E)
{
    int e = blockIdx.x*4 + (threadIdx.x >> 6);
    if (e >= E) return;
    int lane = threadIdx.x & 63;
    int s = src[e], d = dst[e];
    float a = __expf(score[e] - funflip(smax[d])) / ssum[d];
    float4 l4 = *(const float4*)(el + (size_t)s*D + lane*4);
    float* o = out + (size_t)d*D + lane*4;
    atomicAdd(o+0, a*l4.x);
    atomicAdd(o+1, a*l4.y);
    atomicAdd(o+2, a*l4.z);
    atomicAdd(o+3, a*l4.w);
}

extern "C" void kernel_launch(void* const* d_in, const int* in_sizes, int n_in,
                              void* d_out, int out_size, void* d_ws, size_t ws_size,
                              hipStream_t stream)
{
    const float* feat = (const float*)d_in[0];
    const float* Wsrc = (const float*)d_in[1];
    const float* bsrc = (const float*)d_in[2];
    const float* Wdst = (const float*)d_in[3];
    const float* bdst = (const float*)d_in[4];
    const float* attn = (const float*)d_in[5];
    const int*   src  = (const int*)d_in[6];
    const int*   dst  = (const int*)d_in[7];
    const int N = in_sizes[0] / D;
    const int E = in_sizes[6];
    float* out = (float*)d_out;

    // workspace layout: el[N*D] er[N*D] score[E] smax[N] ssum[N]  (~207 MB)
    float*    el    = (float*)d_ws;
    float*    er    = el + (size_t)N*D;
    float*    score = er + (size_t)N*D;
    unsigned* smax  = (unsigned*)(score + E);
    float*    ssum  = (float*)(smax + N);

    init_kernel<<<2048, 256, 0, stream>>>((float4*)out, (size_t)N*D/4, smax, ssum, (size_t)N);
    dim3 pgrid((N + 63)/64, D/64, 2);
    proj_kernel<<<pgrid, 256, 0, stream>>>(feat, Wsrc, bsrc, Wdst, bdst, el, er, N);
    score_kernel<<<(E + 3)/4, 256, 0, stream>>>(el, er, attn, src, dst, score, smax, E);
    expsum_kernel<<<(E + 255)/256, 256, 0, stream>>>(score, dst, smax, ssum, E);
    aggregate_kernel<<<(E + 3)/4, 256, 0, stream>>>(el, score, src, dst, smax, ssum, out, E);
}

// Round 2
// 483.551 us; speedup vs baseline: 3.0271x; 3.0271x over previous
//
#include <hip/hip_runtime.h>
#include <cstdint>
#include <cmath>

#define D 256
#define NEG 0.2f

// ---------------- projection GEMMs (unchanged this round) ----------------
// el = feat@Wsrc + bsrc (z=0), er = feat@Wdst + bdst (z=1)
__global__ __launch_bounds__(256) void proj_kernel(
    const float* __restrict__ feat,
    const float* __restrict__ Wsrc, const float* __restrict__ bsrc,
    const float* __restrict__ Wdst, const float* __restrict__ bdst,
    float* __restrict__ el, float* __restrict__ er, int N)
{
    const int which = blockIdx.z;
    const float* __restrict__ W    = which ? Wdst : Wsrc;
    const float* __restrict__ bias = which ? bdst : bsrc;
    float* __restrict__ out        = which ? er : el;

    const int row0 = blockIdx.x * 64;
    const int col0 = blockIdx.y * 64;

    __shared__ float As[64][36];
    __shared__ float Bs[32][68];

    const int tid = threadIdx.x;
    const int tx = tid & 15;
    const int ty = tid >> 4;
    float acc[4][4] = {};

    const int arow = tid >> 3;
    const int af4  = (tid & 7) * 4;
    const int brow = tid >> 4;
    const int bf4  = (tid & 15) * 4;

    for (int k0 = 0; k0 < D; k0 += 32) {
        #pragma unroll
        for (int rr = 0; rr < 2; ++rr) {
            int r = arow + rr*32;
            int gr = row0 + r;
            float4 v = make_float4(0.f,0.f,0.f,0.f);
            if (gr < N) v = *(const float4*)(feat + (size_t)gr*D + k0 + af4);
            *(float4*)&As[r][af4] = v;
        }
        #pragma unroll
        for (int rr = 0; rr < 2; ++rr) {
            int r = brow + rr*16;
            float4 v = *(const float4*)(W + (size_t)(k0 + r)*D + col0 + bf4);
            *(float4*)&Bs[r][bf4] = v;
        }
        __syncthreads();
        #pragma unroll
        for (int kk = 0; kk < 32; ++kk) {
            float a[4], b[4];
            #pragma unroll
            for (int i = 0; i < 4; ++i) a[i] = As[ty*4+i][kk];
            #pragma unroll
            for (int j = 0; j < 4; ++j) b[j] = Bs[kk][tx*4+j];
            #pragma unroll
            for (int i = 0; i < 4; ++i)
                #pragma unroll
                for (int j = 0; j < 4; ++j)
                    acc[i][j] += a[i]*b[j];
        }
        __syncthreads();
    }
    #pragma unroll
    for (int i = 0; i < 4; ++i) {
        int gr = row0 + ty*4 + i;
        if (gr >= N) continue;
        int gc = col0 + tx*4;
        float4 b4 = *(const float4*)(bias + gc);
        float4 v = make_float4(acc[i][0]+b4.x, acc[i][1]+b4.y,
                               acc[i][2]+b4.z, acc[i][3]+b4.w);
        *(float4*)(out + (size_t)gr*D + gc) = v;
    }
}

// ---------------- CSR build ----------------
__global__ void count_kernel(const int* __restrict__ dst, int* __restrict__ deg, int E){
    int e = blockIdx.x*blockDim.x + threadIdx.x;
    if (e < E) atomicAdd(&deg[dst[e]], 1);
}

// inclusive scan within 256-blocks; write block totals
__global__ __launch_bounds__(256) void scan1_kernel(const int* __restrict__ deg,
                                                    int* __restrict__ incl,
                                                    int* __restrict__ bsum, int N){
    __shared__ int s[256];
    int i = blockIdx.x*256 + threadIdx.x;
    int v = (i < N) ? deg[i] : 0;
    s[threadIdx.x] = v;
    __syncthreads();
    #pragma unroll
    for (int off = 1; off < 256; off <<= 1){
        int t = (threadIdx.x >= off) ? s[threadIdx.x - off] : 0;
        __syncthreads();
        s[threadIdx.x] += t;
        __syncthreads();
    }
    if (i < N) incl[i] = s[threadIdx.x];
    if (threadIdx.x == 255) bsum[blockIdx.x] = s[255];
}

// exclusive scan of block totals (nb <= 512), single block
__global__ __launch_bounds__(512) void scan2_kernel(int* __restrict__ bsum, int nb){
    __shared__ int s[512];
    int t = threadIdx.x;
    int v = (t < nb) ? bsum[t] : 0;
    s[t] = v;
    __syncthreads();
    #pragma unroll
    for (int off = 1; off < 512; off <<= 1){
        int u = (t >= off) ? s[t - off] : 0;
        __syncthreads();
        s[t] += u;
        __syncthreads();
    }
    if (t < nb) bsum[t] = s[t] - v;   // exclusive
}

__global__ __launch_bounds__(256) void scan3_kernel(const int* __restrict__ deg,
                                                    const int* __restrict__ incl,
                                                    const int* __restrict__ bsum,
                                                    int* __restrict__ rowstart,
                                                    int* __restrict__ cursor, int N){
    int i = blockIdx.x*256 + threadIdx.x;
    if (i < N){
        int st = incl[i] - deg[i] + bsum[blockIdx.x];
        rowstart[i] = st;
        cursor[i]   = st;
    }
}

__global__ void scatter_kernel(const int* __restrict__ dst, int* __restrict__ cursor,
                               int* __restrict__ eid, int E){
    int e = blockIdx.x*blockDim.x + threadIdx.x;
    if (e < E){
        int pos = atomicAdd(&cursor[dst[e]], 1);
        eid[pos] = e;
    }
}

// ---------------- fused score + online-softmax + aggregate ----------------
// one wave per dst node
__global__ __launch_bounds__(256) void gat_node_kernel(
    const float* __restrict__ el, const float* __restrict__ er,
    const float* __restrict__ attn, const int* __restrict__ src,
    const int* __restrict__ eid, const int* __restrict__ rowstart,
    const int* __restrict__ degv, float* __restrict__ out, int N)
{
    int node = blockIdx.x*4 + (threadIdx.x >> 6);
    if (node >= N) return;
    int lane = threadIdx.x & 63;
    float4 o = make_float4(0.f,0.f,0.f,0.f);
    int deg = degv[node];
    float* op = out + (size_t)node*D + lane*4;
    if (deg == 0){ *(float4*)op = o; return; }

    float4 r4 = *(const float4*)(er + (size_t)node*D + lane*4);
    float4 a4 = *(const float4*)(attn + lane*4);
    int start = rowstart[node];

    float m = -INFINITY, ssum = 0.f;
    for (int k = 0; k < deg; ++k){
        int e  = eid[start + k];
        int sn = src[e];
        float4 l4 = *(const float4*)(el + (size_t)sn*D + lane*4);
        float x, p = 0.f;
        x = l4.x + r4.x; p += (x > 0.f ? x : NEG*x) * a4.x;
        x = l4.y + r4.y; p += (x > 0.f ? x : NEG*x) * a4.y;
        x = l4.z + r4.z; p += (x > 0.f ? x : NEG*x) * a4.z;
        x = l4.w + r4.w; p += (x > 0.f ? x : NEG*x) * a4.w;
        #pragma unroll
        for (int off = 32; off > 0; off >>= 1) p += __shfl_xor(p, off, 64);
        // online softmax update
        float newm  = fmaxf(m, p);
        float scale = __expf(m - newm);     // first iter: exp(-inf)=0
        float w     = __expf(p - newm);
        ssum = ssum*scale + w;
        o.x = o.x*scale + w*l4.x;
        o.y = o.y*scale + w*l4.y;
        o.z = o.z*scale + w*l4.z;
        o.w = o.w*scale + w*l4.w;
        m = newm;
    }
    float inv = 1.f/ssum;
    o.x *= inv; o.y *= inv; o.z *= inv; o.w *= inv;
    *(float4*)op = o;
}

extern "C" void kernel_launch(void* const* d_in, const int* in_sizes, int n_in,
                              void* d_out, int out_size, void* d_ws, size_t ws_size,
                              hipStream_t stream)
{
    const float* feat = (const float*)d_in[0];
    const float* Wsrc = (const float*)d_in[1];
    const float* bsrc = (const float*)d_in[2];
    const float* Wdst = (const float*)d_in[3];
    const float* bdst = (const float*)d_in[4];
    const float* attn = (const float*)d_in[5];
    const int*   src  = (const int*)d_in[6];
    const int*   dst  = (const int*)d_in[7];
    const int N = in_sizes[0] / D;
    const int E = in_sizes[6];
    float* out = (float*)d_out;

    // workspace: el[N*D] er[N*D] | deg incl rowstart cursor (N each) | bsum[512] | eid[E]
    float* el = (float*)d_ws;
    float* er = el + (size_t)N*D;
    int* deg      = (int*)(er + (size_t)N*D);
    int* incl     = deg + N;
    int* rowstart = incl + N;
    int* cursor   = rowstart + N;
    int* bsum     = cursor + N;
    int* eid      = bsum + 512;

    const int nb = (N + 255)/256;

    hipMemsetAsync(deg, 0, (size_t)N*sizeof(int), stream);

    dim3 pgrid((N + 63)/64, D/64, 2);
    proj_kernel<<<pgrid, 256, 0, stream>>>(feat, Wsrc, bsrc, Wdst, bdst, el, er, N);

    count_kernel<<<(E + 255)/256, 256, 0, stream>>>(dst, deg, E);
    scan1_kernel<<<nb, 256, 0, stream>>>(deg, incl, bsum, N);
    scan2_kernel<<<1, 512, 0, stream>>>(bsum, nb);
    scan3_kernel<<<nb, 256, 0, stream>>>(deg, incl, bsum, rowstart, cursor, N);
    scatter_kernel<<<(E + 255)/256, 256, 0, stream>>>(dst, cursor, eid, E);

    gat_node_kernel<<<(N + 3)/4, 256, 0, stream>>>(el, er, attn, src, eid,
                                                   rowstart, deg, out, N);
}

// Round 3
// 313.419 us; speedup vs baseline: 4.6702x; 1.5428x over previous
//
#include <hip/hip_runtime.h>
#include <cstdint>
#include <cmath>

#define D 256
#define NEG 0.2f
#define LDA 40   // padded LDS row length in ushorts (80 B: 16B-aligned rows, ~2-way banks)

typedef __attribute__((ext_vector_type(8))) __bf16 bf16x8;
typedef __attribute__((ext_vector_type(8))) unsigned short ushort8;
typedef __attribute__((ext_vector_type(4))) float f32x4;

__device__ __forceinline__ unsigned short f2bf(float f){
    unsigned u = __float_as_uint(f);
    return (unsigned short)((u + 0x7fffu + ((u >> 16) & 1u)) >> 16);  // RNE
}

// ---- prep: WT[col][k] = bf16(W[k][col]) for col<256 -> Wsrc, else Wdst; biascat ----
__global__ __launch_bounds__(256) void prep_kernel(
    const float* __restrict__ Wsrc, const float* __restrict__ Wdst,
    const float* __restrict__ bsrc, const float* __restrict__ bdst,
    unsigned short* __restrict__ WT, float* __restrict__ biascat)
{
    int idx = blockIdx.x*256 + threadIdx.x;     // 512*256 = 131072 total
    int col = idx >> 8;
    int k   = idx & 255;
    const float* W = (col < 256) ? Wsrc : Wdst;
    int c = col & 255;
    WT[(size_t)col*D + k] = f2bf(W[(size_t)k*D + c]);
    if (idx < 512) biascat[idx] = (idx < 256) ? bsrc[idx] : bdst[idx-256];
}

// ---- bf16 MFMA projection: C[N][512] = feat @ [Wsrc|Wdst] + bias, split to el/er ----
// 128x128 tile, BK=32, 256 threads (4 waves, 2x2), 4x4 16x16x32 frags per wave
__global__ __launch_bounds__(256) void proj_mfma_kernel(
    const float* __restrict__ feat, const unsigned short* __restrict__ WT,
    const float* __restrict__ biascat,
    float* __restrict__ el, float* __restrict__ er, int N)
{
    __shared__ unsigned short As[128*LDA];
    __shared__ unsigned short Bs[128*LDA];

    const int tid  = threadIdx.x;
    const int wave = tid >> 6;
    const int lane = tid & 63;
    const int row0 = blockIdx.x * 128;
    const int col0 = blockIdx.y * 128;
    const int wr = (wave >> 1) * 64;
    const int wc = (wave & 1) * 64;
    const int l15 = lane & 15;
    const int kg  = lane >> 4;          // 0..3

    const int arow  = tid >> 3;         // 0..31, 4 passes of 32 rows
    const int acol4 = (tid & 7) * 4;    // f32 k-offset
    const int brow  = tid >> 2;         // 0..63, 2 passes of 64 rows
    const int bcol8 = (tid & 3) * 8;    // ushort k-offset

    f32x4 acc[4][4] = {};

    for (int k0 = 0; k0 < D; k0 += 32) {
        #pragma unroll
        for (int rr = 0; rr < 4; ++rr) {
            int r = arow + rr*32;
            int gr = row0 + r;
            float4 v = make_float4(0.f,0.f,0.f,0.f);
            if (gr < N) v = *(const float4*)(feat + (size_t)gr*D + k0 + acol4);
            ushort4 b;
            b.x = f2bf(v.x); b.y = f2bf(v.y); b.z = f2bf(v.z); b.w = f2bf(v.w);
            *(ushort4*)&As[r*LDA + acol4] = b;
        }
        #pragma unroll
        for (int rr = 0; rr < 2; ++rr) {
            int r = brow + rr*64;
            ushort8 v = *(const ushort8*)(WT + (size_t)(col0 + r)*D + k0 + bcol8);
            *(ushort8*)&Bs[r*LDA + bcol8] = v;
        }
        __syncthreads();

        bf16x8 af[4], bf[4];
        #pragma unroll
        for (int m = 0; m < 4; ++m)
            af[m] = *(const bf16x8*)&As[(wr + m*16 + l15)*LDA + kg*8];
        #pragma unroll
        for (int n = 0; n < 4; ++n)
            bf[n] = *(const bf16x8*)&Bs[(wc + n*16 + l15)*LDA + kg*8];
        #pragma unroll
        for (int m = 0; m < 4; ++m)
            #pragma unroll
            for (int n = 0; n < 4; ++n)
                acc[m][n] = __builtin_amdgcn_mfma_f32_16x16x32_bf16(af[m], bf[n], acc[m][n], 0, 0, 0);
        __syncthreads();
    }

    // epilogue: C col = lane&15 (+n*16), row = kg*4 + j (+m*16)  [m89 mapping]
    #pragma unroll
    for (int n = 0; n < 4; ++n) {
        int col = col0 + wc + n*16 + l15;
        float bias = biascat[col];
        float* dstp = (col < 256) ? el : er;
        int cc = col & 255;
        #pragma unroll
        for (int m = 0; m < 4; ++m) {
            #pragma unroll
            for (int j = 0; j < 4; ++j) {
                int row = row0 + wr + m*16 + kg*4 + j;
                if (row < N)
                    dstp[(size_t)row*D + cc] = acc[m][n][j] + bias;
            }
        }
    }
}

// ---------------- CSR build ----------------
__global__ void count_kernel(const int* __restrict__ dst, int* __restrict__ deg, int E){
    int e = blockIdx.x*blockDim.x + threadIdx.x;
    if (e < E) atomicAdd(&deg[dst[e]], 1);
}

__global__ __launch_bounds__(256) void scan1_kernel(const int* __restrict__ deg,
                                                    int* __restrict__ incl,
                                                    int* __restrict__ bsum, int N){
    __shared__ int s[256];
    int i = blockIdx.x*256 + threadIdx.x;
    int v = (i < N) ? deg[i] : 0;
    s[threadIdx.x] = v;
    __syncthreads();
    #pragma unroll
    for (int off = 1; off < 256; off <<= 1){
        int t = (threadIdx.x >= off) ? s[threadIdx.x - off] : 0;
        __syncthreads();
        s[threadIdx.x] += t;
        __syncthreads();
    }
    if (i < N) incl[i] = s[threadIdx.x];
    if (threadIdx.x == 255) bsum[blockIdx.x] = s[255];
}

__global__ __launch_bounds__(512) void scan2_kernel(int* __restrict__ bsum, int nb){
    __shared__ int s[512];
    int t = threadIdx.x;
    int v = (t < nb) ? bsum[t] : 0;
    s[t] = v;
    __syncthreads();
    #pragma unroll
    for (int off = 1; off < 512; off <<= 1){
        int u = (t >= off) ? s[t - off] : 0;
        __syncthreads();
        s[t] += u;
        __syncthreads();
    }
    if (t < nb) bsum[t] = s[t] - v;   // exclusive
}

__global__ __launch_bounds__(256) void scan3_kernel(const int* __restrict__ deg,
                                                    const int* __restrict__ incl,
                                                    const int* __restrict__ bsum,
                                                    int* __restrict__ rowstart,
                                                    int* __restrict__ cursor, int N){
    int i = blockIdx.x*256 + threadIdx.x;
    if (i < N){
        int st = incl[i] - deg[i] + bsum[blockIdx.x];
        rowstart[i] = st;
        cursor[i]   = st;
    }
}

__global__ void scatter_kernel(const int* __restrict__ dst, int* __restrict__ cursor,
                               int* __restrict__ eid, int E){
    int e = blockIdx.x*blockDim.x + threadIdx.x;
    if (e < E){
        int pos = atomicAdd(&cursor[dst[e]], 1);
        eid[pos] = e;
    }
}

// ---------------- fused score + online-softmax + aggregate (one wave / dst) -------
__global__ __launch_bounds__(256) void gat_node_kernel(
    const float* __restrict__ el, const float* __restrict__ er,
    const float* __restrict__ attn, const int* __restrict__ src,
    const int* __restrict__ eid, const int* __restrict__ rowstart,
    const int* __restrict__ degv, float* __restrict__ out, int N)
{
    int node = blockIdx.x*4 + (threadIdx.x >> 6);
    if (node >= N) return;
    int lane = threadIdx.x & 63;
    float4 o = make_float4(0.f,0.f,0.f,0.f);
    int deg = degv[node];
    float* op = out + (size_t)node*D + lane*4;
    if (deg == 0){ *(float4*)op = o; return; }

    float4 r4 = *(const float4*)(er + (size_t)node*D + lane*4);
    float4 a4 = *(const float4*)(attn + lane*4);
    int start = rowstart[node];

    float m = -INFINITY, ssum = 0.f;
    for (int k = 0; k < deg; ++k){
        int e  = eid[start + k];
        int sn = src[e];
        float4 l4 = *(const float4*)(el + (size_t)sn*D + lane*4);
        float x, p = 0.f;
        x = l4.x + r4.x; p += (x > 0.f ? x : NEG*x) * a4.x;
        x = l4.y + r4.y; p += (x > 0.f ? x : NEG*x) * a4.y;
        x = l4.z + r4.z; p += (x > 0.f ? x : NEG*x) * a4.z;
        x = l4.w + r4.w; p += (x > 0.f ? x : NEG*x) * a4.w;
        #pragma unroll
        for (int off = 32; off > 0; off >>= 1) p += __shfl_xor(p, off, 64);
        float newm  = fmaxf(m, p);
        float scale = __expf(m - newm);
        float w     = __expf(p - newm);
        ssum = ssum*scale + w;
        o.x = o.x*scale + w*l4.x;
        o.y = o.y*scale + w*l4.y;
        o.z = o.z*scale + w*l4.z;
        o.w = o.w*scale + w*l4.w;
        m = newm;
    }
    float inv = 1.f/ssum;
    o.x *= inv; o.y *= inv; o.z *= inv; o.w *= inv;
    *(float4*)op = o;
}

extern "C" void kernel_launch(void* const* d_in, const int* in_sizes, int n_in,
                              void* d_out, int out_size, void* d_ws, size_t ws_size,
                              hipStream_t stream)
{
    const float* feat = (const float*)d_in[0];
    const float* Wsrc = (const float*)d_in[1];
    const float* bsrc = (const float*)d_in[2];
    const float* Wdst = (const float*)d_in[3];
    const float* bdst = (const float*)d_in[4];
    const float* attn = (const float*)d_in[5];
    const int*   src  = (const int*)d_in[6];
    const int*   dst  = (const int*)d_in[7];
    const int N = in_sizes[0] / D;
    const int E = in_sizes[6];
    float* out = (float*)d_out;

    // ws: el[N*D] er[N*D] | deg incl rowstart cursor (N ints) | bsum[512] | eid[E]
    //     | WT[512*256 ushort] | biascat[512 f32]
    float* el = (float*)d_ws;
    float* er = el + (size_t)N*D;
    int* deg      = (int*)(er + (size_t)N*D);
    int* incl     = deg + N;
    int* rowstart = incl + N;
    int* cursor   = rowstart + N;
    int* bsum     = cursor + N;
    int* eid      = bsum + 512;
    unsigned short* WT = (unsigned short*)(eid + E);
    float* biascat = (float*)(WT + (size_t)512*D);

    const int nb = (N + 255)/256;

    hipMemsetAsync(deg, 0, (size_t)N*sizeof(int), stream);

    prep_kernel<<<512, 256, 0, stream>>>(Wsrc, Wdst, bsrc, bdst, WT, biascat);

    dim3 pgrid((N + 127)/128, 4);
    proj_mfma_kernel<<<pgrid, 256, 0, stream>>>(feat, WT, biascat, el, er, N);

    count_kernel<<<(E + 255)/256, 256, 0, stream>>>(dst, deg, E);
    scan1_kernel<<<nb, 256, 0, stream>>>(deg, incl, bsum, N);
    scan2_kernel<<<1, 512, 0, stream>>>(bsum, nb);
    scan3_kernel<<<nb, 256, 0, stream>>>(deg, incl, bsum, rowstart, cursor, N);
    scatter_kernel<<<(E + 255)/256, 256, 0, stream>>>(dst, cursor, eid, E);

    gat_node_kernel<<<(N + 3)/4, 256, 0, stream>>>(el, er, attn, src, eid,
                                                   rowstart, deg, out, N);
}

// Round 7
// 256.547 us; speedup vs baseline: 5.7055x; 1.2217x over previous
//
#include <hip/hip_runtime.h>
#include <cstdint>
#include <cmath>

#define D 256
#define NEG 0.2f
#define LDA 40   // padded LDS row length in ushorts (80 B rows: 16B-aligned, ~2-way banks = free)

typedef __attribute__((ext_vector_type(8))) __bf16 bf16x8;
typedef __attribute__((ext_vector_type(8))) unsigned short ushort8;
typedef __attribute__((ext_vector_type(4))) float f32x4;

__device__ __forceinline__ unsigned short f2bf(float f){
    unsigned u = __float_as_uint(f);
    return (unsigned short)((u + 0x7fffu + ((u >> 16) & 1u)) >> 16);  // RNE
}
__device__ __forceinline__ float b2f(unsigned short u){
    return __uint_as_float(((unsigned)u) << 16);
}

// ---- prep: WT[col][k] = bf16(W[k][col]) for col<256 -> Wsrc, else Wdst; biascat ----
__global__ __launch_bounds__(256) void prep_kernel(
    const float* __restrict__ Wsrc, const float* __restrict__ Wdst,
    const float* __restrict__ bsrc, const float* __restrict__ bdst,
    unsigned short* __restrict__ WT, float* __restrict__ biascat)
{
    int idx = blockIdx.x*256 + threadIdx.x;     // 512*256 = 131072 total
    int col = idx >> 8;
    int k   = idx & 255;
    const float* W = (col < 256) ? Wsrc : Wdst;
    int c = col & 255;
    WT[(size_t)col*D + k] = f2bf(W[(size_t)k*D + c]);
    if (idx < 512) biascat[idx] = (idx < 256) ? bsrc[idx] : bdst[idx-256];
}

// ---- bf16 MFMA projection: C[N][512] = feat @ [Wsrc|Wdst] + bias -> el16/er16 (bf16) ----
// grid: (4 col-blocks fastest, row-blocks) so the 4 col-blocks of one feat panel run
// concurrently and share the panel via L2/L3 (fetch feat ONCE from HBM).
// 128x128 tile, BK=32, 256 threads (4 waves, 2x2), 4x4 16x16x32 frags per wave.
// MFMA called with SWAPPED operands -> lane holds C^T frag: row = lane&15 (+m*16),
// cols = kg*4+j (+n*16)  => one ushort4 bf16 store per frag (coalesced 8B).
__global__ __launch_bounds__(256) void proj_mfma_kernel(
    const float* __restrict__ feat, const unsigned short* __restrict__ WT,
    const float* __restrict__ biascat,
    unsigned short* __restrict__ el16, unsigned short* __restrict__ er16, int N)
{
    __shared__ unsigned short As[128*LDA];
    __shared__ unsigned short Bs[128*LDA];

    const int tid  = threadIdx.x;
    const int wave = tid >> 6;
    const int lane = tid & 63;
    const int col0 = blockIdx.x * 128;   // fastest dim: 0,128,256,384
    const int row0 = blockIdx.y * 128;
    const int wr = (wave >> 1) * 64;
    const int wc = (wave & 1) * 64;
    const int l15 = lane & 15;
    const int kg  = lane >> 4;          // 0..3

    const int arow  = tid >> 3;         // 0..31, 4 passes of 32 rows
    const int acol4 = (tid & 7) * 4;    // f32 k-offset
    const int brow  = tid >> 2;         // 0..63, 2 passes of 64 rows
    const int bcol8 = (tid & 3) * 8;    // ushort k-offset

    f32x4 acc[4][4] = {};

    for (int k0 = 0; k0 < D; k0 += 32) {
        #pragma unroll
        for (int rr = 0; rr < 4; ++rr) {
            int r = arow + rr*32;
            int gr = row0 + r;
            float4 v = make_float4(0.f,0.f,0.f,0.f);
            if (gr < N) v = *(const float4*)(feat + (size_t)gr*D + k0 + acol4);
            ushort4 b;
            b.x = f2bf(v.x); b.y = f2bf(v.y); b.z = f2bf(v.z); b.w = f2bf(v.w);
            *(ushort4*)&As[r*LDA + acol4] = b;
        }
        #pragma unroll
        for (int rr = 0; rr < 2; ++rr) {
            int r = brow + rr*64;
            ushort8 v = *(const ushort8*)(WT + (size_t)(col0 + r)*D + k0 + bcol8);
            *(ushort8*)&Bs[r*LDA + bcol8] = v;
        }
        __syncthreads();

        bf16x8 af[4], bfr[4];
        #pragma unroll
        for (int m = 0; m < 4; ++m)
            af[m] = *(const bf16x8*)&As[(wr + m*16 + l15)*LDA + kg*8];
        #pragma unroll
        for (int n = 0; n < 4; ++n)
            bfr[n] = *(const bf16x8*)&Bs[(wc + n*16 + l15)*LDA + kg*8];
        #pragma unroll
        for (int m = 0; m < 4; ++m)
            #pragma unroll
            for (int n = 0; n < 4; ++n)
                acc[m][n] = __builtin_amdgcn_mfma_f32_16x16x32_bf16(bfr[n], af[m], acc[m][n], 0, 0, 0);
        __syncthreads();
    }

    // epilogue: C^T frag -> row = row0+wr+m*16+l15, cols = col0+wc+n*16+kg*4 .. +3
    unsigned short* __restrict__ dstp = (col0 < 256) ? el16 : er16;
    const int ccbase = col0 & 255;
    #pragma unroll
    for (int m = 0; m < 4; ++m) {
        int row = row0 + wr + m*16 + l15;
        if (row >= N) continue;
        #pragma unroll
        for (int n = 0; n < 4; ++n) {
            int cw = wc + n*16 + kg*4;            // 0..127 within block
            float4 b4 = *(const float4*)(biascat + col0 + cw);
            ushort4 o;
            o.x = f2bf(acc[m][n][0] + b4.x);
            o.y = f2bf(acc[m][n][1] + b4.y);
            o.z = f2bf(acc[m][n][2] + b4.z);
            o.w = f2bf(acc[m][n][3] + b4.w);
            *(ushort4*)(dstp + (size_t)row*D + ccbase + cw) = o;
        }
    }
}

// ---------------- CSR build ----------------
__global__ void count_kernel(const int* __restrict__ dst, int* __restrict__ deg, int E){
    int e = blockIdx.x*blockDim.x + threadIdx.x;
    if (e < E) atomicAdd(&deg[dst[e]], 1);
}

__global__ __launch_bounds__(256) void scan1_kernel(const int* __restrict__ deg,
                                                    int* __restrict__ incl,
                                                    int* __restrict__ bsum, int N){
    __shared__ int s[256];
    int i = blockIdx.x*256 + threadIdx.x;
    int v = (i < N) ? deg[i] : 0;
    s[threadIdx.x] = v;
    __syncthreads();
    #pragma unroll
    for (int off = 1; off < 256; off <<= 1){
        int t = (threadIdx.x >= off) ? s[threadIdx.x - off] : 0;
        __syncthreads();
        s[threadIdx.x] += t;
        __syncthreads();
    }
    if (i < N) incl[i] = s[threadIdx.x];
    if (threadIdx.x == 255) bsum[blockIdx.x] = s[255];
}

__global__ __launch_bounds__(512) void scan2_kernel(int* __restrict__ bsum, int nb){
    __shared__ int s[512];
    int t = threadIdx.x;
    int v = (t < nb) ? bsum[t] : 0;
    s[t] = v;
    __syncthreads();
    #pragma unroll
    for (int off = 1; off < 512; off <<= 1){
        int u = (t >= off) ? s[t - off] : 0;
        __syncthreads();
        s[t] += u;
        __syncthreads();
    }
    if (t < nb) bsum[t] = s[t] - v;   // exclusive
}

__global__ __launch_bounds__(256) void scan3_kernel(const int* __restrict__ deg,
                                                    const int* __restrict__ incl,
                                                    const int* __restrict__ bsum,
                                                    int* __restrict__ rowstart,
                                                    int* __restrict__ cursor, int N){
    int i = blockIdx.x*256 + threadIdx.x;
    if (i < N){
        int st = incl[i] - deg[i] + bsum[blockIdx.x];
        rowstart[i] = st;
        cursor[i]   = st;
    }
}

__global__ void scatter_kernel(const int* __restrict__ dst, int* __restrict__ cursor,
                               int* __restrict__ eid, int E){
    int e = blockIdx.x*blockDim.x + threadIdx.x;
    if (e < E){
        int pos = atomicAdd(&cursor[dst[e]], 1);
        eid[pos] = e;
    }
}

// ---------------- fused score + online-softmax + aggregate (one wave / dst) -------
// el/er are bf16 rows (512 B): wave reads ushort4 (8 B) per lane.
__global__ __launch_bounds__(256) void gat_node_kernel(
    const unsigned short* __restrict__ el16, const unsigned short* __restrict__ er16,
    const float* __restrict__ attn, const int* __restrict__ src,
    const int* __restrict__ eid, const int* __restrict__ rowstart,
    const int* __restrict__ degv, float* __restrict__ out, int N)
{
    int node = blockIdx.x*4 + (threadIdx.x >> 6);
    if (node >= N) return;
    int lane = threadIdx.x & 63;
    float4 o = make_float4(0.f,0.f,0.f,0.f);
    int deg = degv[node];
    float* op = out + (size_t)node*D + lane*4;
    if (deg == 0){ *(float4*)op = o; return; }

    ushort4 rv = *(const ushort4*)(er16 + (size_t)node*D + lane*4);
    float4 r4 = make_float4(b2f(rv.x), b2f(rv.y), b2f(rv.z), b2f(rv.w));
    float4 a4 = *(const float4*)(attn + lane*4);
    int start = rowstart[node];

    float m = -INFINITY, ssum = 0.f;
    for (int k = 0; k < deg; ++k){
        int e  = eid[start + k];
        int sn = src[e];
        ushort4 lv = *(const ushort4*)(el16 + (size_t)sn*D + lane*4);
        float4 l4 = make_float4(b2f(lv.x), b2f(lv.y), b2f(lv.z), b2f(lv.w));
        float x, p = 0.f;
        x = l4.x + r4.x; p += (x > 0.f ? x : NEG*x) * a4.x;
        x = l4.y + r4.y; p += (x > 0.f ? x : NEG*x) * a4.y;
        x = l4.z + r4.z; p += (x > 0.f ? x : NEG*x) * a4.z;
        x = l4.w + r4.w; p += (x > 0.f ? x : NEG*x) * a4.w;
        #pragma unroll
        for (int off = 32; off > 0; off >>= 1) p += __shfl_xor(p, off, 64);
        float newm  = fmaxf(m, p);
        float scale = __expf(m - newm);
        float w     = __expf(p - newm);
        ssum = ssum*scale + w;
        o.x = o.x*scale + w*l4.x;
        o.y = o.y*scale + w*l4.y;
        o.z = o.z*scale + w*l4.z;
        o.w = o.w*scale + w*l4.w;
        m = newm;
    }
    float inv = 1.f/ssum;
    o.x *= inv; o.y *= inv; o.z *= inv; o.w *= inv;
    *(float4*)op = o;
}

extern "C" void kernel_launch(void* const* d_in, const int* in_sizes, int n_in,
                              void* d_out, int out_size, void* d_ws, size_t ws_size,
                              hipStream_t stream)
{
    const float* feat = (const float*)d_in[0];
    const float* Wsrc = (const float*)d_in[1];
    const float* bsrc = (const float*)d_in[2];
    const float* Wdst = (const float*)d_in[3];
    const float* bdst = (const float*)d_in[4];
    const float* attn = (const float*)d_in[5];
    const int*   src  = (const int*)d_in[6];
    const int*   dst  = (const int*)d_in[7];
    const int N = in_sizes[0] / D;
    const int E = in_sizes[6];
    float* out = (float*)d_out;

    // ws: el16[N*D] er16[N*D] (ushort) | deg incl rowstart cursor (N ints) | bsum[512]
    //     | eid[E] | WT[512*256 ushort] | biascat[512 f32]
    unsigned short* el16 = (unsigned short*)d_ws;
    unsigned short* er16 = el16 + (size_t)N*D;
    int* deg      = (int*)(er16 + (size_t)N*D);
    int* incl     = deg + N;
    int* rowstart = incl + N;
    int* cursor   = rowstart + N;
    int* bsum     = cursor + N;
    int* eid      = bsum + 512;
    unsigned short* WT = (unsigned short*)(eid + E);
    float* biascat = (float*)(WT + (size_t)512*D);

    const int nb = (N + 255)/256;

    hipMemsetAsync(deg, 0, (size_t)N*sizeof(int), stream);

    prep_kernel<<<512, 256, 0, stream>>>(Wsrc, Wdst, bsrc, bdst, WT, biascat);

    dim3 pgrid(4, (N + 127)/128);   // col-blocks fastest: share feat panel via L2/L3
    proj_mfma_kernel<<<pgrid, 256, 0, stream>>>(feat, WT, biascat, el16, er16, N);

    count_kernel<<<(E + 255)/256, 256, 0, stream>>>(dst, deg, E);
    scan1_kernel<<<nb, 256, 0, stream>>>(deg, incl, bsum, N);
    scan2_kernel<<<1, 512, 0, stream>>>(bsum, nb);
    scan3_kernel<<<nb, 256, 0, stream>>>(deg, incl, bsum, rowstart, cursor, N);
    scatter_kernel<<<(E + 255)/256, 256, 0, stream>>>(dst, cursor, eid, E);

    gat_node_kernel<<<(N + 3)/4, 256, 0, stream>>>(el16, er16, attn, src, eid,
                                                   rowstart, deg, out, N);
}

// Round 9
// 213.994 us; speedup vs baseline: 6.8401x; 1.1989x over previous
//
#include <hip/hip_runtime.h>
#include <cstdint>
#include <cmath>

#define D 256
#define NEG 0.2f
#define BK 64

typedef __attribute__((ext_vector_type(8))) __bf16 bf16x8;
typedef __attribute__((ext_vector_type(8))) unsigned short ushort8;
typedef __attribute__((ext_vector_type(4))) float f32x4;

__device__ __forceinline__ unsigned short f2bf(float f){
    unsigned u = __float_as_uint(f);
    return (unsigned short)((u + 0x7fffu + ((u >> 16) & 1u)) >> 16);  // RNE
}
__device__ __forceinline__ float b2f(unsigned short u){
    return __uint_as_float(((unsigned)u) << 16);
}

// async global->LDS, 16B per lane; LDS dest is WAVE-UNIFORM base (+lane*16 by HW)
__device__ __forceinline__ void gload_lds16(const void* g, void* l){
    __builtin_amdgcn_global_load_lds(
        (const __attribute__((address_space(1))) unsigned int*)g,
        (__attribute__((address_space(3))) unsigned int*)l, 16, 0, 0);
}

// ---- prep W: WT[col][k] bf16, transposed, SWIZZLED: dest 16B-unit u holds orig unit
// (u&24)|((u^col)&7). col<256 -> Wsrc else Wdst. Also biascat.
__global__ __launch_bounds__(256) void prep_w_kernel(
    const float* __restrict__ Wsrc, const float* __restrict__ Wdst,
    const float* __restrict__ bsrc, const float* __restrict__ bdst,
    unsigned short* __restrict__ WT, float* __restrict__ biascat)
{
    int idx = blockIdx.x*256 + threadIdx.x;     // 512 cols * 32 units = 16384
    int col = idx >> 5;
    int u   = idx & 31;
    int gu  = (u & 24) | ((u ^ col) & 7);
    const float* W = (col < 256) ? Wsrc : Wdst;
    int c = col & 255;
    ushort8 o;
    #pragma unroll
    for (int j = 0; j < 8; ++j)
        o[j] = f2bf(W[(size_t)(gu*8 + j)*D + c]);
    *(ushort8*)(WT + (size_t)col*D + u*8) = o;
    if (idx < 512) biascat[idx] = (idx < 256) ? bsrc[idx] : bdst[idx-256];
}

// ---- prep feat: featb[r][*] = bf16(feat[r][*]), unit-swizzled like WT, zero-padded to NPAD
__global__ __launch_bounds__(256) void prep_feat_kernel(
    const float* __restrict__ feat, unsigned short* __restrict__ featb, int N, int NPAD)
{
    int total = NPAD * 32;   // 16B units
    for (int idx = blockIdx.x*256 + threadIdx.x; idx < total; idx += gridDim.x*256){
        int r = idx >> 5;
        int u = idx & 31;
        ushort8 o;
        if (r < N){
            int gu = (u & 24) | ((u ^ r) & 7);
            const float* s = feat + (size_t)r*D + gu*8;
            float4 a = *(const float4*)s;
            float4 b = *(const float4*)(s + 4);
            o[0]=f2bf(a.x); o[1]=f2bf(a.y); o[2]=f2bf(a.z); o[3]=f2bf(a.w);
            o[4]=f2bf(b.x); o[5]=f2bf(b.y); o[6]=f2bf(b.z); o[7]=f2bf(b.w);
        } else {
            #pragma unroll
            for (int j = 0; j < 8; ++j) o[j] = 0;
        }
        *(ushort8*)(featb + (size_t)r*D + u*8) = o;
    }
}

// ---- bf16 MFMA projection, m97-style: global_load_lds staging, BK=64, swizzled LDS ----
// C[N][512] = featb @ WT^T + bias -> el16 (cols<256) / er16. 128x128 tile, 4 waves 2x2,
// swapped-operand MFMA (C^T frags) -> coalesced ushort4 bf16 stores.
__global__ __launch_bounds__(256) void proj_mfma_kernel(
    const unsigned short* __restrict__ featb, const unsigned short* __restrict__ WT,
    const float* __restrict__ biascat,
    unsigned short* __restrict__ el16, unsigned short* __restrict__ er16, int N)
{
    __shared__ unsigned short As[128*BK];   // 16 KB, rows 128B, swizzled content
    __shared__ unsigned short Bs[128*BK];   // 16 KB

    const int tid  = threadIdx.x;
    const int wave = tid >> 6;
    const int lane = tid & 63;
    const int col0 = blockIdx.x * 128;   // fastest: 4 col-blocks share feat panel
    const int row0 = blockIdx.y * 128;
    const int wr = (wave >> 1) * 64;
    const int wc = (wave & 1) * 64;
    const int l15 = lane & 15;
    const int kg  = lane >> 4;          // 0..3

    // staging geometry: per round, wave stages 1KB = 8 rows; lane -> (row, unit)
    const int sr = (wave << 3) + (lane >> 3);   // row within 32-row chunk
    const int sc = (lane & 7) * 8;              // elem offset of 16B unit

    f32x4 acc[4][4] = {};

    for (int k0 = 0; k0 < D; k0 += BK) {
        #pragma unroll
        for (int r4 = 0; r4 < 4; ++r4) {
            int ar = r4*32 + sr;
            gload_lds16(featb + (size_t)(row0 + ar)*D + k0 + sc,
                        &As[(r4*32 + wave*8)*BK]);
            gload_lds16(WT + (size_t)(col0 + ar)*D + k0 + sc,
                        &Bs[(r4*32 + wave*8)*BK]);
        }
        __syncthreads();   // compiler emits vmcnt(0) drain here (correctness)

        #pragma unroll
        for (int ks = 0; ks < 2; ++ks) {
            bf16x8 af[4], bfr[4];
            #pragma unroll
            for (int m = 0; m < 4; ++m){
                int row = wr + m*16 + l15;
                int c = ((kg + ks*4) ^ (row & 7)) * 8;   // un-swizzle on read
                af[m] = *(const bf16x8*)&As[row*BK + c];
            }
            #pragma unroll
            for (int n = 0; n < 4; ++n){
                int row = wc + n*16 + l15;
                int c = ((kg + ks*4) ^ (row & 7)) * 8;
                bfr[n] = *(const bf16x8*)&Bs[row*BK + c];
            }
            #pragma unroll
            for (int m = 0; m < 4; ++m)
                #pragma unroll
                for (int n = 0; n < 4; ++n)
                    acc[m][n] = __builtin_amdgcn_mfma_f32_16x16x32_bf16(bfr[n], af[m], acc[m][n], 0, 0, 0);
        }
        __syncthreads();
    }

    // epilogue: C^T frag -> row = row0+wr+m*16+l15, cols = col0+wc+n*16+kg*4 .. +3
    unsigned short* __restrict__ dstp = (col0 < 256) ? el16 : er16;
    const int ccbase = col0 & 255;
    #pragma unroll
    for (int m = 0; m < 4; ++m) {
        int row = row0 + wr + m*16 + l15;
        if (row >= N) continue;
        #pragma unroll
        for (int n = 0; n < 4; ++n) {
            int cw = wc + n*16 + kg*4;
            float4 b4 = *(const float4*)(biascat + col0 + cw);
            ushort4 o;
            o.x = f2bf(acc[m][n][0] + b4.x);
            o.y = f2bf(acc[m][n][1] + b4.y);
            o.z = f2bf(acc[m][n][2] + b4.z);
            o.w = f2bf(acc[m][n][3] + b4.w);
            *(ushort4*)(dstp + (size_t)row*D + ccbase + cw) = o;
        }
    }
}

// ---------------- CSR build ----------------
__global__ void count_kernel(const int* __restrict__ dst, int* __restrict__ deg, int E){
    int e = blockIdx.x*blockDim.x + threadIdx.x;
    if (e < E) atomicAdd(&deg[dst[e]], 1);
}

__global__ __launch_bounds__(256) void scan1_kernel(const int* __restrict__ deg,
                                                    int* __restrict__ incl,
                                                    int* __restrict__ bsum, int N){
    __shared__ int s[256];
    int i = blockIdx.x*256 + threadIdx.x;
    int v = (i < N) ? deg[i] : 0;
    s[threadIdx.x] = v;
    __syncthreads();
    #pragma unroll
    for (int off = 1; off < 256; off <<= 1){
        int t = (threadIdx.x >= off) ? s[threadIdx.x - off] : 0;
        __syncthreads();
        s[threadIdx.x] += t;
        __syncthreads();
    }
    if (i < N) incl[i] = s[threadIdx.x];
    if (threadIdx.x == 255) bsum[blockIdx.x] = s[255];
}

__global__ __launch_bounds__(512) void scan2_kernel(int* __restrict__ bsum, int nb){
    __shared__ int s[512];
    int t = threadIdx.x;
    int v = (t < nb) ? bsum[t] : 0;
    s[t] = v;
    __syncthreads();
    #pragma unroll
    for (int off = 1; off < 512; off <<= 1){
        int u = (t >= off) ? s[t - off] : 0;
        __syncthreads();
        s[t] += u;
        __syncthreads();
    }
    if (t < nb) bsum[t] = s[t] - v;   // exclusive
}

__global__ __launch_bounds__(256) void scan3_kernel(const int* __restrict__ deg,
                                                    const int* __restrict__ incl,
                                                    const int* __restrict__ bsum,
                                                    int* __restrict__ rowstart,
                                                    int* __restrict__ cursor, int N){
    int i = blockIdx.x*256 + threadIdx.x;
    if (i < N){
        int st = incl[i] - deg[i] + bsum[blockIdx.x];
        rowstart[i] = st;
        cursor[i]   = st;
    }
}

__global__ void scatter_kernel(const int* __restrict__ dst, int* __restrict__ cursor,
                               int* __restrict__ eid, int E){
    int e = blockIdx.x*blockDim.x + threadIdx.x;
    if (e < E){
        int pos = atomicAdd(&cursor[dst[e]], 1);
        eid[pos] = e;
    }
}

// ---------------- fused score + online-softmax + aggregate (one wave / dst) -------
__global__ __launch_bounds__(256) void gat_node_kernel(
    const unsigned short* __restrict__ el16, const unsigned short* __restrict__ er16,
    const float* __restrict__ attn, const int* __restrict__ src,
    const int* __restrict__ eid, const int* __restrict__ rowstart,
    const int* __restrict__ degv, float* __restrict__ out, int N)
{
    int node = blockIdx.x*4 + (threadIdx.x >> 6);
    if (node >= N) return;
    int lane = threadIdx.x & 63;
    float4 o = make_float4(0.f,0.f,0.f,0.f);
    int deg = degv[node];
    float* op = out + (size_t)node*D + lane*4;
    if (deg == 0){ *(float4*)op = o; return; }

    ushort4 rv = *(const ushort4*)(er16 + (size_t)node*D + lane*4);
    float4 r4 = make_float4(b2f(rv.x), b2f(rv.y), b2f(rv.z), b2f(rv.w));
    float4 a4 = *(const float4*)(attn + lane*4);
    int start = rowstart[node];

    float m = -INFINITY, ssum = 0.f;
    for (int k = 0; k < deg; ++k){
        int e  = eid[start + k];
        int sn = src[e];
        ushort4 lv = *(const ushort4*)(el16 + (size_t)sn*D + lane*4);
        float4 l4 = make_float4(b2f(lv.x), b2f(lv.y), b2f(lv.z), b2f(lv.w));
        float x, p = 0.f;
        x = l4.x + r4.x; p += (x > 0.f ? x : NEG*x) * a4.x;
        x = l4.y + r4.y; p += (x > 0.f ? x : NEG*x) * a4.y;
        x = l4.z + r4.z; p += (x > 0.f ? x : NEG*x) * a4.z;
        x = l4.w + r4.w; p += (x > 0.f ? x : NEG*x) * a4.w;
        #pragma unroll
        for (int off = 32; off > 0; off >>= 1) p += __shfl_xor(p, off, 64);
        float newm  = fmaxf(m, p);
        float scale = __expf(m - newm);
        float w     = __expf(p - newm);
        ssum = ssum*scale + w;
        o.x = o.x*scale + w*l4.x;
        o.y = o.y*scale + w*l4.y;
        o.z = o.z*scale + w*l4.z;
        o.w = o.w*scale + w*l4.w;
        m = newm;
    }
    float inv = 1.f/ssum;
    o.x *= inv; o.y *= inv; o.z *= inv; o.w *= inv;
    *(float4*)op = o;
}

extern "C" void kernel_launch(void* const* d_in, const int* in_sizes, int n_in,
                              void* d_out, int out_size, void* d_ws, size_t ws_size,
                              hipStream_t stream)
{
    const float* feat = (const float*)d_in[0];
    const float* Wsrc = (const float*)d_in[1];
    const float* bsrc = (const float*)d_in[2];
    const float* Wdst = (const float*)d_in[3];
    const float* bdst = (const float*)d_in[4];
    const float* attn = (const float*)d_in[5];
    const int*   src  = (const int*)d_in[6];
    const int*   dst  = (const int*)d_in[7];
    const int N = in_sizes[0] / D;
    const int E = in_sizes[6];
    const int NPAD = ((N + 127)/128)*128;
    float* out = (float*)d_out;

    // ws: el16[N*D] er16[N*D] | deg incl rowstart cursor (N ints) | bsum[512] | eid[E]
    //     | WT[512*256] | biascat[512 f32] | featb[NPAD*256]
    unsigned short* el16 = (unsigned short*)d_ws;
    unsigned short* er16 = el16 + (size_t)N*D;
    int* deg      = (int*)(er16 + (size_t)N*D);
    int* incl     = deg + N;
    int* rowstart = incl + N;
    int* cursor   = rowstart + N;
    int* bsum     = cursor + N;
    int* eid      = bsum + 512;
    unsigned short* WT = (unsigned short*)(eid + E);
    float* biascat = (float*)(WT + (size_t)512*D);
    unsigned short* featb = (unsigned short*)(biascat + 512);

    const int nb = (N + 255)/256;

    hipMemsetAsync(deg, 0, (size_t)N*sizeof(int), stream);

    prep_w_kernel<<<64, 256, 0, stream>>>(Wsrc, Wdst, bsrc, bdst, WT, biascat);
    prep_feat_kernel<<<4096, 256, 0, stream>>>(feat, featb, N, NPAD);

    dim3 pgrid(4, NPAD/128);   // col-blocks fastest
    proj_mfma_kernel<<<pgrid, 256, 0, stream>>>(featb, WT, biascat, el16, er16, N);

    count_kernel<<<(E + 255)/256, 256, 0, stream>>>(dst, deg, E);
    scan1_kernel<<<nb, 256, 0, stream>>>(deg, incl, bsum, N);
    scan2_kernel<<<1, 512, 0, stream>>>(bsum, nb);
    scan3_kernel<<<nb, 256, 0, stream>>>(deg, incl, bsum, rowstart, cursor, N);
    scatter_kernel<<<(E + 255)/256, 256, 0, stream>>>(dst, cursor, eid, E);

    gat_node_kernel<<<(N + 3)/4, 256, 0, stream>>>(el16, er16, attn, src, eid,
                                                   rowstart, deg, out, N);
}

// Round 10
// 189.608 us; speedup vs baseline: 7.7198x; 1.1286x over previous
//
#include <hip/hip_runtime.h>
#include <cstdint>
#include <cmath>

#define D 256
#define NEG 0.2f
#define BK 64

typedef __attribute__((ext_vector_type(8))) __bf16 bf16x8;
typedef __attribute__((ext_vector_type(8))) unsigned short ushort8;
typedef __attribute__((ext_vector_type(4))) float f32x4;

__device__ __forceinline__ unsigned short f2bf(float f){
    unsigned u = __float_as_uint(f);
    return (unsigned short)((u + 0x7fffu + ((u >> 16) & 1u)) >> 16);  // RNE
}
__device__ __forceinline__ float b2f(unsigned short u){
    return __uint_as_float(((unsigned)u) << 16);
}

// async global->LDS, 16B per lane; LDS dest is WAVE-UNIFORM base (+lane*16 by HW)
__device__ __forceinline__ void gload_lds16(const void* g, void* l){
    __builtin_amdgcn_global_load_lds(
        (const __attribute__((address_space(1))) unsigned int*)g,
        (__attribute__((address_space(3))) unsigned int*)l, 16, 0, 0);
}

// ---- prep W: WT[col][k] bf16, transposed, SWIZZLED: dest 16B-unit u holds orig unit
// (u&24)|((u^col)&7). col<256 -> Wsrc else Wdst. Also biascat.
__global__ __launch_bounds__(256) void prep_w_kernel(
    const float* __restrict__ Wsrc, const float* __restrict__ Wdst,
    const float* __restrict__ bsrc, const float* __restrict__ bdst,
    unsigned short* __restrict__ WT, float* __restrict__ biascat)
{
    int idx = blockIdx.x*256 + threadIdx.x;     // 512 cols * 32 units = 16384
    int col = idx >> 5;
    int u   = idx & 31;
    int gu  = (u & 24) | ((u ^ col) & 7);
    const float* W = (col < 256) ? Wsrc : Wdst;
    int c = col & 255;
    ushort8 o;
    #pragma unroll
    for (int j = 0; j < 8; ++j)
        o[j] = f2bf(W[(size_t)(gu*8 + j)*D + c]);
    *(ushort8*)(WT + (size_t)col*D + u*8) = o;
    if (idx < 512) biascat[idx] = (idx < 256) ? bsrc[idx] : bdst[idx-256];
}

// ---- prep feat: featb[r][*] = bf16(feat[r][*]), unit-swizzled like WT, zero-padded to NPAD
__global__ __launch_bounds__(256) void prep_feat_kernel(
    const float* __restrict__ feat, unsigned short* __restrict__ featb, int N, int NPAD)
{
    int total = NPAD * 32;   // 16B units
    for (int idx = blockIdx.x*256 + threadIdx.x; idx < total; idx += gridDim.x*256){
        int r = idx >> 5;
        int u = idx & 31;
        ushort8 o;
        if (r < N){
            int gu = (u & 24) | ((u ^ r) & 7);
            const float* s = feat + (size_t)r*D + gu*8;
            float4 a = *(const float4*)s;
            float4 b = *(const float4*)(s + 4);
            o[0]=f2bf(a.x); o[1]=f2bf(a.y); o[2]=f2bf(a.z); o[3]=f2bf(a.w);
            o[4]=f2bf(b.x); o[5]=f2bf(b.y); o[6]=f2bf(b.z); o[7]=f2bf(b.w);
        } else {
            #pragma unroll
            for (int j = 0; j < 8; ++j) o[j] = 0;
        }
        *(ushort8*)(featb + (size_t)r*D + u*8) = o;
    }
}

// ---- bf16 MFMA projection, m97-style: global_load_lds staging, BK=64, swizzled LDS ----
__global__ __launch_bounds__(256) void proj_mfma_kernel(
    const unsigned short* __restrict__ featb, const unsigned short* __restrict__ WT,
    const float* __restrict__ biascat,
    unsigned short* __restrict__ el16, unsigned short* __restrict__ er16, int N)
{
    __shared__ unsigned short As[128*BK];   // 16 KB, rows 128B, swizzled content
    __shared__ unsigned short Bs[128*BK];   // 16 KB

    const int tid  = threadIdx.x;
    const int wave = tid >> 6;
    const int lane = tid & 63;
    const int col0 = blockIdx.x * 128;   // fastest: 4 col-blocks share feat panel
    const int row0 = blockIdx.y * 128;
    const int wr = (wave >> 1) * 64;
    const int wc = (wave & 1) * 64;
    const int l15 = lane & 15;
    const int kg  = lane >> 4;          // 0..3

    const int sr = (wave << 3) + (lane >> 3);   // row within 32-row chunk
    const int sc = (lane & 7) * 8;              // elem offset of 16B unit

    f32x4 acc[4][4] = {};

    for (int k0 = 0; k0 < D; k0 += BK) {
        #pragma unroll
        for (int r4 = 0; r4 < 4; ++r4) {
            int ar = r4*32 + sr;
            gload_lds16(featb + (size_t)(row0 + ar)*D + k0 + sc,
                        &As[(r4*32 + wave*8)*BK]);
            gload_lds16(WT + (size_t)(col0 + ar)*D + k0 + sc,
                        &Bs[(r4*32 + wave*8)*BK]);
        }
        __syncthreads();

        #pragma unroll
        for (int ks = 0; ks < 2; ++ks) {
            bf16x8 af[4], bfr[4];
            #pragma unroll
            for (int m = 0; m < 4; ++m){
                int row = wr + m*16 + l15;
                int c = ((kg + ks*4) ^ (row & 7)) * 8;   // un-swizzle on read
                af[m] = *(const bf16x8*)&As[row*BK + c];
            }
            #pragma unroll
            for (int n = 0; n < 4; ++n){
                int row = wc + n*16 + l15;
                int c = ((kg + ks*4) ^ (row & 7)) * 8;
                bfr[n] = *(const bf16x8*)&Bs[row*BK + c];
            }
            #pragma unroll
            for (int m = 0; m < 4; ++m)
                #pragma unroll
                for (int n = 0; n < 4; ++n)
                    acc[m][n] = __builtin_amdgcn_mfma_f32_16x16x32_bf16(bfr[n], af[m], acc[m][n], 0, 0, 0);
        }
        __syncthreads();
    }

    unsigned short* __restrict__ dstp = (col0 < 256) ? el16 : er16;
    const int ccbase = col0 & 255;
    #pragma unroll
    for (int m = 0; m < 4; ++m) {
        int row = row0 + wr + m*16 + l15;
        if (row >= N) continue;
        #pragma unroll
        for (int n = 0; n < 4; ++n) {
            int cw = wc + n*16 + kg*4;
            float4 b4 = *(const float4*)(biascat + col0 + cw);
            ushort4 o;
            o.x = f2bf(acc[m][n][0] + b4.x);
            o.y = f2bf(acc[m][n][1] + b4.y);
            o.z = f2bf(acc[m][n][2] + b4.z);
            o.w = f2bf(acc[m][n][3] + b4.w);
            *(ushort4*)(dstp + (size_t)row*D + ccbase + cw) = o;
        }
    }
}

// ---------------- CSR build ----------------
__global__ void count_kernel(const int* __restrict__ dst, int* __restrict__ deg, int E){
    int e = blockIdx.x*blockDim.x + threadIdx.x;
    if (e < E) atomicAdd(&deg[dst[e]], 1);
}

__global__ __launch_bounds__(256) void scan1_kernel(const int* __restrict__ deg,
                                                    int* __restrict__ incl,
                                                    int* __restrict__ bsum, int N){
    __shared__ int s[256];
    int i = blockIdx.x*256 + threadIdx.x;
    int v = (i < N) ? deg[i] : 0;
    s[threadIdx.x] = v;
    __syncthreads();
    #pragma unroll
    for (int off = 1; off < 256; off <<= 1){
        int t = (threadIdx.x >= off) ? s[threadIdx.x - off] : 0;
        __syncthreads();
        s[threadIdx.x] += t;
        __syncthreads();
    }
    if (i < N) incl[i] = s[threadIdx.x];
    if (threadIdx.x == 255) bsum[blockIdx.x] = s[255];
}

__global__ __launch_bounds__(512) void scan2_kernel(int* __restrict__ bsum, int nb){
    __shared__ int s[512];
    int t = threadIdx.x;
    int v = (t < nb) ? bsum[t] : 0;
    s[t] = v;
    __syncthreads();
    #pragma unroll
    for (int off = 1; off < 512; off <<= 1){
        int u = (t >= off) ? s[t - off] : 0;
        __syncthreads();
        s[t] += u;
        __syncthreads();
    }
    if (t < nb) bsum[t] = s[t] - v;   // exclusive
}

__global__ __launch_bounds__(256) void scan3_kernel(const int* __restrict__ deg,
                                                    const int* __restrict__ incl,
                                                    const int* __restrict__ bsum,
                                                    int* __restrict__ rowstart,
                                                    int* __restrict__ cursor, int N){
    int i = blockIdx.x*256 + threadIdx.x;
    if (i < N){
        int st = incl[i] - deg[i] + bsum[blockIdx.x];
        rowstart[i] = st;
        cursor[i]   = st;
    }
}

// write SOURCE NODE id directly into CSR slot (no eid indirection)
__global__ void scatter_kernel(const int* __restrict__ dst, const int* __restrict__ src,
                               int* __restrict__ cursor, int* __restrict__ srcs, int E){
    int e = blockIdx.x*blockDim.x + threadIdx.x;
    if (e < E){
        int pos = atomicAdd(&cursor[dst[e]], 1);
        srcs[pos] = src[e];
    }
}

// ---------------- fused score + online-softmax + aggregate (one wave / dst) -------
// 4-edge batches: 4 gathers in flight, 4 independent shuffle-reduce chains.
__global__ __launch_bounds__(256) void gat_node_kernel(
    const unsigned short* __restrict__ el16, const unsigned short* __restrict__ er16,
    const float* __restrict__ attn, const int* __restrict__ srcs,
    const int* __restrict__ rowstart, const int* __restrict__ degv,
    float* __restrict__ out, int N)
{
    int node = blockIdx.x*4 + (threadIdx.x >> 6);
    if (node >= N) return;
    int lane = threadIdx.x & 63;
    float4 o = make_float4(0.f,0.f,0.f,0.f);
    int deg = degv[node];
    float* op = out + (size_t)node*D + lane*4;
    if (deg == 0){ *(float4*)op = o; return; }

    ushort4 rv = *(const ushort4*)(er16 + (size_t)node*D + lane*4);
    float4 r4 = make_float4(b2f(rv.x), b2f(rv.y), b2f(rv.z), b2f(rv.w));
    float4 a4 = *(const float4*)(attn + lane*4);
    int start = rowstart[node];

    float m = -INFINITY, ssum = 0.f;
    for (int base = 0; base < deg; base += 4){
        int cnt = deg - base; if (cnt > 4) cnt = 4;
        float4 l[4]; float p[4];
        // issue all 4 gathers (clamped index -> unconditional, 4-deep MLP)
        #pragma unroll
        for (int j = 0; j < 4; ++j){
            int k = base + j; if (k >= deg) k = deg - 1;
            int sn = srcs[start + k];
            ushort4 lv = *(const ushort4*)(el16 + (size_t)sn*D + lane*4);
            l[j] = make_float4(b2f(lv.x), b2f(lv.y), b2f(lv.z), b2f(lv.w));
        }
        // 4 independent dot partials
        #pragma unroll
        for (int j = 0; j < 4; ++j){
            float x, pp = 0.f;
            x = l[j].x + r4.x; pp += (x > 0.f ? x : NEG*x) * a4.x;
            x = l[j].y + r4.y; pp += (x > 0.f ? x : NEG*x) * a4.y;
            x = l[j].z + r4.z; pp += (x > 0.f ? x : NEG*x) * a4.z;
            x = l[j].w + r4.w; pp += (x > 0.f ? x : NEG*x) * a4.w;
            p[j] = pp;
        }
        // 4 reduce chains pipeline across the 6 shuffle steps
        #pragma unroll
        for (int off = 32; off > 0; off >>= 1){
            #pragma unroll
            for (int j = 0; j < 4; ++j) p[j] += __shfl_xor(p[j], off, 64);
        }
        // serial online-softmax updates (VALU-only, short)
        #pragma unroll
        for (int j = 0; j < 4; ++j){
            if (j >= cnt) break;
            float newm  = fmaxf(m, p[j]);
            float scale = __expf(m - newm);
            float w     = __expf(p[j] - newm);
            ssum = ssum*scale + w;
            o.x = o.x*scale + w*l[j].x;
            o.y = o.y*scale + w*l[j].y;
            o.z = o.z*scale + w*l[j].z;
            o.w = o.w*scale + w*l[j].w;
            m = newm;
        }
    }
    float inv = 1.f/ssum;
    o.x *= inv; o.y *= inv; o.z *= inv; o.w *= inv;
    *(float4*)op = o;
}

extern "C" void kernel_launch(void* const* d_in, const int* in_sizes, int n_in,
                              void* d_out, int out_size, void* d_ws, size_t ws_size,
                              hipStream_t stream)
{
    const float* feat = (const float*)d_in[0];
    const float* Wsrc = (const float*)d_in[1];
    const float* bsrc = (const float*)d_in[2];
    const float* Wdst = (const float*)d_in[3];
    const float* bdst = (const float*)d_in[4];
    const float* attn = (const float*)d_in[5];
    const int*   src  = (const int*)d_in[6];
    const int*   dst  = (const int*)d_in[7];
    const int N = in_sizes[0] / D;
    const int E = in_sizes[6];
    const int NPAD = ((N + 127)/128)*128;
    float* out = (float*)d_out;

    // ws: el16[N*D] er16[N*D] | deg incl rowstart cursor (N ints) | bsum[512] | srcs[E]
    //     | WT[512*256] | biascat[512 f32] | featb[NPAD*256]
    unsigned short* el16 = (unsigned short*)d_ws;
    unsigned short* er16 = el16 + (size_t)N*D;
    int* deg      = (int*)(er16 + (size_t)N*D);
    int* incl     = deg + N;
    int* rowstart = incl + N;
    int* cursor   = rowstart + N;
    int* bsum     = cursor + N;
    int* srcs     = bsum + 512;
    unsigned short* WT = (unsigned short*)(srcs + E);
    float* biascat = (float*)(WT + (size_t)512*D);
    unsigned short* featb = (unsigned short*)(biascat + 512);

    const int nb = (N + 255)/256;

    hipMemsetAsync(deg, 0, (size_t)N*sizeof(int), stream);

    prep_w_kernel<<<64, 256, 0, stream>>>(Wsrc, Wdst, bsrc, bdst, WT, biascat);
    prep_feat_kernel<<<4096, 256, 0, stream>>>(feat, featb, N, NPAD);

    dim3 pgrid(4, NPAD/128);   // col-blocks fastest
    proj_mfma_kernel<<<pgrid, 256, 0, stream>>>(featb, WT, biascat, el16, er16, N);

    count_kernel<<<(E + 255)/256, 256, 0, stream>>>(dst, deg, E);
    scan1_kernel<<<nb, 256, 0, stream>>>(deg, incl, bsum, N);
    scan2_kernel<<<1, 512, 0, stream>>>(bsum, nb);
    scan3_kernel<<<nb, 256, 0, stream>>>(deg, incl, bsum, rowstart, cursor, N);
    scatter_kernel<<<(E + 255)/256, 256, 0, stream>>>(dst, src, cursor, srcs, E);

    gat_node_kernel<<<(N + 3)/4, 256, 0, stream>>>(el16, er16, attn, srcs,
                                                   rowstart, deg, out, N);
}

// Round 13
// 186.896 us; speedup vs baseline: 7.8318x; 1.0145x over previous
//
#include <hip/hip_runtime.h>
#include <cstdint>
#include <cmath>

#define D 256
#define NEG 0.2f
#define BK 64
#define NT (D/BK)   // 4 K-tiles

typedef __attribute__((ext_vector_type(8))) __bf16 bf16x8;
typedef __attribute__((ext_vector_type(8))) unsigned short ushort8;
typedef __attribute__((ext_vector_type(4))) float f32x4;

__device__ __forceinline__ unsigned short f2bf(float f){
    unsigned u = __float_as_uint(f);
    return (unsigned short)((u + 0x7fffu + ((u >> 16) & 1u)) >> 16);  // RNE
}
__device__ __forceinline__ float b2f(unsigned short u){
    return __uint_as_float(((unsigned)u) << 16);
}

// async global->LDS, 16B per lane; LDS dest is WAVE-UNIFORM base (+lane*16 by HW)
__device__ __forceinline__ void gload_lds16(const void* g, void* l){
    __builtin_amdgcn_global_load_lds(
        (const __attribute__((address_space(1))) unsigned int*)g,
        (__attribute__((address_space(3))) unsigned int*)l, 16, 0, 0);
}

// ---- prep W: WT[col][k] bf16, transposed, unit-swizzled (u&24)|((u^col)&7) ----
__global__ __launch_bounds__(256) void prep_w_kernel(
    const float* __restrict__ Wsrc, const float* __restrict__ Wdst,
    const float* __restrict__ bsrc, const float* __restrict__ bdst,
    unsigned short* __restrict__ WT, float* __restrict__ biascat)
{
    int idx = blockIdx.x*256 + threadIdx.x;     // 512 cols * 32 units = 16384
    int col = idx >> 5;
    int u   = idx & 31;
    int gu  = (u & 24) | ((u ^ col) & 7);
    const float* W = (col < 256) ? Wsrc : Wdst;
    int c = col & 255;
    ushort8 o;
    #pragma unroll
    for (int j = 0; j < 8; ++j)
        o[j] = f2bf(W[(size_t)(gu*8 + j)*D + c]);
    *(ushort8*)(WT + (size_t)col*D + u*8) = o;
    if (idx < 512) biascat[idx] = (idx < 256) ? bsrc[idx] : bdst[idx-256];
}

// ---- prep feat: featb = bf16(feat), unit-swizzled, zero-padded to NPAD rows ----
__global__ __launch_bounds__(256) void prep_feat_kernel(
    const float* __restrict__ feat, unsigned short* __restrict__ featb, int N, int NPAD)
{
    int total = NPAD * 32;   // 16B units
    for (int idx = blockIdx.x*256 + threadIdx.x; idx < total; idx += gridDim.x*256){
        int r = idx >> 5;
        int u = idx & 31;
        ushort8 o;
        if (r < N){
            int gu = (u & 24) | ((u ^ r) & 7);
            const float* s = feat + (size_t)r*D + gu*8;
            float4 a = *(const float4*)s;
            float4 b = *(const float4*)(s + 4);
            o[0]=f2bf(a.x); o[1]=f2bf(a.y); o[2]=f2bf(a.z); o[3]=f2bf(a.w);
            o[4]=f2bf(b.x); o[5]=f2bf(b.y); o[6]=f2bf(b.z); o[7]=f2bf(b.w);
        } else {
            #pragma unroll
            for (int j = 0; j < 8; ++j) o[j] = 0;
        }
        *(ushort8*)(featb + (size_t)r*D + u*8) = o;
    }
}

// ---- bf16 MFMA projection: double-buffered gload_lds staging, counted vmcnt,
// XCD-grouped 1D grid (all 4 col-blocks of a row panel -> same XCD's L2) ----
__global__ __launch_bounds__(256) void proj_mfma_kernel(
    const unsigned short* __restrict__ featb, const unsigned short* __restrict__ WT,
    const float* __restrict__ biascat,
    unsigned short* __restrict__ el16, unsigned short* __restrict__ er16, int N)
{
    __shared__ unsigned short As[2][128*BK];   // 2 x 16 KB
    __shared__ unsigned short Bs[2][128*BK];   // 2 x 16 KB

    // XCD-grouped decode: b%8 = XCD; panel p = (b>>3 / 4)*8 + (b&7); col c = (b>>3)&3
    const int b    = blockIdx.x;
    const int xcd  = b & 7;
    const int s    = b >> 3;
    const int p    = (s >> 2)*8 + xcd;
    const int c    = s & 3;
    const int row0 = p * 128;
    const int col0 = c * 128;

    const int tid  = threadIdx.x;
    const int wave = tid >> 6;
    const int lane = tid & 63;
    const int wr = (wave >> 1) * 64;
    const int wc = (wave & 1) * 64;
    const int l15 = lane & 15;
    const int kg  = lane >> 4;          // 0..3

    const int sr = (wave << 3) + (lane >> 3);   // row within 32-row chunk
    const int sc = (lane & 7) * 8;              // elem offset of 16B unit

    f32x4 acc[4][4] = {};

    // prologue: stage tile 0 into buffer 0 (8 loads/wave)
    #pragma unroll
    for (int r4 = 0; r4 < 4; ++r4) {
        int ar = r4*32 + sr;
        gload_lds16(featb + (size_t)(row0 + ar)*D + 0 + sc, &As[0][(r4*32 + wave*8)*BK]);
        gload_lds16(WT    + (size_t)(col0 + ar)*D + 0 + sc, &Bs[0][(r4*32 + wave*8)*BK]);
    }

    for (int t = 0; t < NT; ++t) {
        const int cur = t & 1;
        // issue next tile's stage into the other buffer (its previous readers
        // finished before the barrier that ended iteration t-1)
        if (t + 1 < NT) {
            int k0 = (t + 1) * BK;
            #pragma unroll
            for (int r4 = 0; r4 < 4; ++r4) {
                int ar = r4*32 + sr;
                gload_lds16(featb + (size_t)(row0 + ar)*D + k0 + sc,
                            &As[cur ^ 1][(r4*32 + wave*8)*BK]);
                gload_lds16(WT    + (size_t)(col0 + ar)*D + k0 + sc,
                            &Bs[cur ^ 1][(r4*32 + wave*8)*BK]);
            }
            asm volatile("s_waitcnt vmcnt(8)" ::: "memory");  // tile t done, t+1 in flight
        } else {
            asm volatile("s_waitcnt vmcnt(0)" ::: "memory");
        }
        __builtin_amdgcn_s_barrier();
        __builtin_amdgcn_sched_barrier(0);

        #pragma unroll
        for (int ks = 0; ks < 2; ++ks) {
            bf16x8 af[4], bfr[4];
            #pragma unroll
            for (int m = 0; m < 4; ++m){
                int row = wr + m*16 + l15;
                int cc = ((kg + ks*4) ^ (row & 7)) * 8;   // un-swizzle on read
                af[m] = *(const bf16x8*)&As[cur][row*BK + cc];
            }
            #pragma unroll
            for (int n = 0; n < 4; ++n){
                int row = wc + n*16 + l15;
                int cc = ((kg + ks*4) ^ (row & 7)) * 8;
                bfr[n] = *(const bf16x8*)&Bs[cur][row*BK + cc];
            }
            #pragma unroll
            for (int m = 0; m < 4; ++m)
                #pragma unroll
                for (int n = 0; n < 4; ++n)
                    acc[m][n] = __builtin_amdgcn_mfma_f32_16x16x32_bf16(bfr[n], af[m], acc[m][n], 0, 0, 0);
        }
        __builtin_amdgcn_sched_barrier(0);
        __builtin_amdgcn_s_barrier();   // all reads of buf[cur] done before it's restaged
    }

    // epilogue: C^T frag -> row = row0+wr+m*16+l15, cols = col0+wc+n*16+kg*4 .. +3
    unsigned short* __restrict__ dstp = (col0 < 256) ? el16 : er16;
    const int ccbase = col0 & 255;
    #pragma unroll
    for (int m = 0; m < 4; ++m) {
        int row = row0 + wr + m*16 + l15;
        if (row >= N) continue;
        #pragma unroll
        for (int n = 0; n < 4; ++n) {
            int cw = wc + n*16 + kg*4;
            float4 b4 = *(const float4*)(biascat + col0 + cw);
            ushort4 o;
            o.x = f2bf(acc[m][n][0] + b4.x);
            o.y = f2bf(acc[m][n][1] + b4.y);
            o.z = f2bf(acc[m][n][2] + b4.z);
            o.w = f2bf(acc[m][n][3] + b4.w);
            *(ushort4*)(dstp + (size_t)row*D + ccbase + cw) = o;
        }
    }
}

// ---------------- CSR build ----------------
__global__ void count_kernel(const int* __restrict__ dst, int* __restrict__ deg, int E){
    int e = blockIdx.x*blockDim.x + threadIdx.x;
    if (e < E) atomicAdd(&deg[dst[e]], 1);
}

__global__ __launch_bounds__(256) void scan1_kernel(const int* __restrict__ deg,
                                                    int* __restrict__ incl,
                                                    int* __restrict__ bsum, int N){
    __shared__ int s[256];
    int i = blockIdx.x*256 + threadIdx.x;
    int v = (i < N) ? deg[i] : 0;
    s[threadIdx.x] = v;
    __syncthreads();
    #pragma unroll
    for (int off = 1; off < 256; off <<= 1){
        int t = (threadIdx.x >= off) ? s[threadIdx.x - off] : 0;
        __syncthreads();
        s[threadIdx.x] += t;
        __syncthreads();
    }
    if (i < N) incl[i] = s[threadIdx.x];
    if (threadIdx.x == 255) bsum[blockIdx.x] = s[255];
}

__global__ __launch_bounds__(512) void scan2_kernel(int* __restrict__ bsum, int nb){
    __shared__ int s[512];
    int t = threadIdx.x;
    int v = (t < nb) ? bsum[t] : 0;
    s[t] = v;
    __syncthreads();
    #pragma unroll
    for (int off = 1; off < 512; off <<= 1){
        int u = (t >= off) ? s[t - off] : 0;
        __syncthreads();
        s[t] += u;
        __syncthreads();
    }
    if (t < nb) bsum[t] = s[t] - v;   // exclusive
}

__global__ __launch_bounds__(256) void scan3_kernel(const int* __restrict__ deg,
                                                    const int* __restrict__ incl,
                                                    const int* __restrict__ bsum,
                                                    int* __restrict__ rowstart,
                                                    int* __restrict__ cursor, int N){
    int i = blockIdx.x*256 + threadIdx.x;
    if (i < N){
        int st = incl[i] - deg[i] + bsum[blockIdx.x];
        rowstart[i] = st;
        cursor[i]   = st;
    }
}

// write SOURCE NODE id directly into CSR slot (no eid indirection)
__global__ void scatter_kernel(const int* __restrict__ dst, const int* __restrict__ src,
                               int* __restrict__ cursor, int* __restrict__ srcs, int E){
    int e = blockIdx.x*blockDim.x + threadIdx.x;
    if (e < E){
        int pos = atomicAdd(&cursor[dst[e]], 1);
        srcs[pos] = src[e];
    }
}

// ---------------- fused score + online-softmax + aggregate (one wave / dst) -------
// 4-edge batches: 4 gathers in flight, 4 independent shuffle-reduce chains.
__global__ __launch_bounds__(256) void gat_node_kernel(
    const unsigned short* __restrict__ el16, const unsigned short* __restrict__ er16,
    const float* __restrict__ attn, const int* __restrict__ srcs,
    const int* __restrict__ rowstart, const int* __restrict__ degv,
    float* __restrict__ out, int N)
{
    int node = blockIdx.x*4 + (threadIdx.x >> 6);
    if (node >= N) return;
    int lane = threadIdx.x & 63;
    float4 o = make_float4(0.f,0.f,0.f,0.f);
    int deg = degv[node];
    float* op = out + (size_t)node*D + lane*4;
    if (deg == 0){ *(float4*)op = o; return; }

    ushort4 rv = *(const ushort4*)(er16 + (size_t)node*D + lane*4);
    float4 r4 = make_float4(b2f(rv.x), b2f(rv.y), b2f(rv.z), b2f(rv.w));
    float4 a4 = *(const float4*)(attn + lane*4);
    int start = rowstart[node];

    float m = -INFINITY, ssum = 0.f;
    for (int base = 0; base < deg; base += 4){
        int cnt = deg - base; if (cnt > 4) cnt = 4;
        float4 l[4]; float p[4];
        #pragma unroll
        for (int j = 0; j < 4; ++j){
            int k = base + j; if (k >= deg) k = deg - 1;
            int sn = srcs[start + k];
            ushort4 lv = *(const ushort4*)(el16 + (size_t)sn*D + lane*4);
            l[j] = make_float4(b2f(lv.x), b2f(lv.y), b2f(lv.z), b2f(lv.w));
        }
        #pragma unroll
        for (int j = 0; j < 4; ++j){
            float x, pp = 0.f;
            x = l[j].x + r4.x; pp += (x > 0.f ? x : NEG*x) * a4.x;
            x = l[j].y + r4.y; pp += (x > 0.f ? x : NEG*x) * a4.y;
            x = l[j].z + r4.z; pp += (x > 0.f ? x : NEG*x) * a4.z;
            x = l[j].w + r4.w; pp += (x > 0.f ? x : NEG*x) * a4.w;
            p[j] = pp;
        }
        #pragma unroll
        for (int off = 32; off > 0; off >>= 1){
            #pragma unroll
            for (int j = 0; j < 4; ++j) p[j] += __shfl_xor(p[j], off, 64);
        }
        #pragma unroll
        for (int j = 0; j < 4; ++j){
            if (j >= cnt) break;
            float newm  = fmaxf(m, p[j]);
            float scale = __expf(m - newm);
            float w     = __expf(p[j] - newm);
            ssum = ssum*scale + w;
            o.x = o.x*scale + w*l[j].x;
            o.y = o.y*scale + w*l[j].y;
            o.z = o.z*scale + w*l[j].z;
            o.w = o.w*scale + w*l[j].w;
            m = newm;
        }
    }
    float inv = 1.f/ssum;
    o.x *= inv; o.y *= inv; o.z *= inv; o.w *= inv;
    *(float4*)op = o;
}

extern "C" void kernel_launch(void* const* d_in, const int* in_sizes, int n_in,
                              void* d_out, int out_size, void* d_ws, size_t ws_size,
                              hipStream_t stream)
{
    const float* feat = (const float*)d_in[0];
    const float* Wsrc = (const float*)d_in[1];
    const float* bsrc = (const float*)d_in[2];
    const float* Wdst = (const float*)d_in[3];
    const float* bdst = (const float*)d_in[4];
    const float* attn = (const float*)d_in[5];
    const int*   src  = (const int*)d_in[6];
    const int*   dst  = (const int*)d_in[7];
    const int N = in_sizes[0] / D;
    const int E = in_sizes[6];
    const int NPAD = ((N + 1023)/1024)*1024;   // panels (NPAD/128) divisible by 8
    const int NP = NPAD / 128;
    float* out = (float*)d_out;

    // ws: el16[N*D] er16[N*D] | deg incl rowstart cursor (N ints) | bsum[512] | srcs[E]
    //     | WT[512*256] | biascat[512 f32] | featb[NPAD*256]
    unsigned short* el16 = (unsigned short*)d_ws;
    unsigned short* er16 = el16 + (size_t)N*D;
    int* deg      = (int*)(er16 + (size_t)N*D);
    int* incl     = deg + N;
    int* rowstart = incl + N;
    int* cursor   = rowstart + N;
    int* bsum     = cursor + N;
    int* srcs     = bsum + 512;
    unsigned short* WT = (unsigned short*)(srcs + E);
    float* biascat = (float*)(WT + (size_t)512*D);
    unsigned short* featb = (unsigned short*)(biascat + 512);

    const int nb = (N + 255)/256;

    hipMemsetAsync(deg, 0, (size_t)N*sizeof(int), stream);

    prep_w_kernel<<<64, 256, 0, stream>>>(Wsrc, Wdst, bsrc, bdst, WT, biascat);
    prep_feat_kernel<<<4096, 256, 0, stream>>>(feat, featb, N, NPAD);

    proj_mfma_kernel<<<4*NP, 256, 0, stream>>>(featb, WT, biascat, el16, er16, N);

    count_kernel<<<(E + 255)/256, 256, 0, stream>>>(dst, deg, E);
    scan1_kernel<<<nb, 256, 0, stream>>>(deg, incl, bsum, N);
    scan2_kernel<<<1, 512, 0, stream>>>(bsum, nb);
    scan3_kernel<<<nb, 256, 0, stream>>>(deg, incl, bsum, rowstart, cursor, N);
    scatter_kernel<<<(E + 255)/256, 256, 0, stream>>>(dst, src, cursor, srcs, E);

    gat_node_kernel<<<(N + 3)/4, 256, 0, stream>>>(el16, er16, attn, srcs,
                                                   rowstart, deg, out, N);
}